// Round 11
// baseline (253.783 us; speedup 1.0000x reference)
//
#include <hip/hip_runtime.h>

// Delta scan, speculative-segment parallelization (exact two-kernel scheme).
//
// R6-R10 evidence: four intra-wave pipeline structures (barriers, none, reg
// prefetch depth 2, global_load_lds DMA) all land 83-138 us at 1.5-2.5 TB/s
// with IDEAL traffic and VALUBusy <= 8%. Invariant: 4 waves/CU (one thread
// per row grid cap). The fill kernel at full occupancy hits 6.2 TB/s ->
// occupancy is the wall. Fix parallelism, not the pipeline.
//
// Kernel 1: 8 segments/row x 65536 rows = 524288 threads (16 waves/CU).
//   Each thread scans its 64-elem segment with TRUE pre = x[seg_start-1]
//   but SPECULATIVE res_in = 0; writes outputs + res_out[row][seg] to ws.
// Kernel 2: 1 thread/row. Carry res across segments; a segment whose true
//   res_in == 0 is exact. Else replay true+spec trajectories from segment
//   start (identical fp ops), overwriting out, until both fire at the same
//   step -> states coincide (res=0, same pre) -> speculative suffix is
//   bit-exact. P(fire/step) ~ 0.94 -> fix-up is ~1 element per boundary.
//
// Stores (K1): line-complete per instruction via wave-private LDS transpose
// (R6: partial-line instrs = 2.31x write amp; R7: full-line instrs = 1.0x).
// Swizzle i^(lane&7): 2 lanes/bank both phases (R7/R8: 0 conflicts).

#define T_LEN 512

constexpr int SEGS   = 8;
constexpr int SEGLEN = T_LEN / SEGS;   // 64 elements
constexpr int SEGF4  = SEGLEN / 4;     // 16 float4
constexpr int BLOCK1 = 256;            // 4 waves; wave = 8 rows x 8 segs
constexpr int BLOCK2 = 256;

__global__ __launch_bounds__(BLOCK1, 4) void delta_seg_kernel(
    const float* __restrict__ x,
    const float* __restrict__ thrp,
    float* __restrict__ out,
    float* __restrict__ res_ws)
{
    // 8 KB per wave (64 lanes x 8 f4), 32 KB/block -> 4 blocks/CU = 16 waves/CU
    __shared__ float4 tile[BLOCK1 / 64][64 * 8];

    const int tid  = threadIdx.x;
    const int wid  = tid >> 6;
    const int lane = tid & 63;
    const int g    = blockIdx.x * BLOCK1 + tid;
    const int row  = g >> 3;                 // g / SEGS
    const int s    = g & 7;                  // segment within row
    const int row0 = (blockIdx.x * BLOCK1 + wid * 64) >> 3;  // wave's first row

    const float thr = fmaxf(thrp[0], 0.015625f);

    const size_t base = (size_t)row * T_LEN + (size_t)s * SEGLEN;  // elem units
    const float4* __restrict__ xv = reinterpret_cast<const float4*>(x);
    float4* __restrict__       ov = reinterpret_cast<float4*>(out);

    // true pre; speculative res_in = 0
    float pre = 0.0f;
    if (s != 0) pre = x[base - 1];
    float res = 0.0f;

    // whole segment in flight (16 contiguous f4 per thread)
    float4 v[SEGF4];
#pragma unroll
    for (int i = 0; i < SEGF4; ++i) v[i] = xv[(base >> 2) + i];

    float4* const wt = tile[wid];

#pragma unroll
    for (int pass = 0; pass < 2; ++pass) {
        // scan 32 elements -> q[0..7]
        float4 q[8];
#pragma unroll
        for (int i = 0; i < 8; ++i) {
            const float4 vv = v[pass * 8 + i];
            float4 qq;
            // exact reference op order: d=(x-pre)+res; y=|d|>=thr?d:0;
            // res=d-y (==b?0:d bit-exact); out=floor(y*64)*2^-6 (exact)
            { float d=(vv.x-pre)+res; bool b=fabsf(d)>=thr; float y=b?d:0.0f;
              res=b?0.0f:d; pre=vv.x; qq.x=floorf(y*64.0f)*0.015625f; }
            { float d=(vv.y-pre)+res; bool b=fabsf(d)>=thr; float y=b?d:0.0f;
              res=b?0.0f:d; pre=vv.y; qq.y=floorf(y*64.0f)*0.015625f; }
            { float d=(vv.z-pre)+res; bool b=fabsf(d)>=thr; float y=b?d:0.0f;
              res=b?0.0f:d; pre=vv.z; qq.z=floorf(y*64.0f)*0.015625f; }
            { float d=(vv.w-pre)+res; bool b=fabsf(d)>=thr; float y=b?d:0.0f;
              res=b?0.0f:d; pre=vv.w; qq.w=floorf(y*64.0f)*0.015625f; }
            q[i] = qq;
        }

        // stage swizzled (2 lanes/bank per instruction)
#pragma unroll
        for (int i = 0; i < 8; ++i)
            wt[lane * 8 + (i ^ (lane & 7))] = q[i];

        // store rounds: round k covers row (row0+k): 8 segments' pass-piece
        // (128B each = ONE full line per 8-lane group; 8 lines/instruction).
        // lane L -> seg = L>>3, f4 = pass*8 + (L&7); source lane S = k*8+(L>>3).
#pragma unroll
        for (int k = 0; k < 8; ++k) {
            const int S  = k * 8 + (lane >> 3);
            const float4 t4 = wt[S * 8 + ((lane & 7) ^ (S & 7))];
            ov[(size_t)(row0 + k) * (T_LEN / 4)
               + (lane >> 3) * SEGF4 + pass * 8 + (lane & 7)] = t4;
        }
        // WAR pass0-read vs pass1-write: wave-private tile, in-order DS pipe
        // (validated R8-R10, absmax=0). No barriers anywhere.
    }

    res_ws[g] = res;   // speculative res_out for this segment
}

__global__ __launch_bounds__(BLOCK2) void delta_fix_kernel(
    const float* __restrict__ x,
    const float* __restrict__ thrp,
    float* __restrict__ out,
    const float* __restrict__ res_ws)
{
    const int row = blockIdx.x * BLOCK2 + threadIdx.x;
    const float thr = fmaxf(thrp[0], 0.015625f);

    // segment 0's speculation (res_in = 0) is exact by construction
    float res = res_ws[row * SEGS + 0];

    for (int s = 1; s < SEGS; ++s) {
        if (res == 0.0f) {           // true res_in matches speculation: exact
            res = res_ws[row * SEGS + s];
            continue;
        }
        const size_t base = (size_t)row * T_LEN + (size_t)s * SEGLEN;
        float pre    = x[base - 1];
        float res_tr = res;          // true trajectory
        float res_sp = 0.0f;         // replay of kernel 1's speculation
        bool  conv   = false;
        for (int t = 0; t < SEGLEN; ++t) {
            const float xi  = x[base + t];
            const float dtr = (xi - pre) + res_tr;
            const float dsp = (xi - pre) + res_sp;
            const bool  ftr = fabsf(dtr) >= thr;
            const bool  fsp = fabsf(dsp) >= thr;
            const float y   = ftr ? dtr : 0.0f;
            out[base + t]   = floorf(y * 64.0f) * 0.015625f;  // overwrite
            res_tr = ftr ? 0.0f : dtr;
            res_sp = fsp ? 0.0f : dsp;
            pre = xi;
            if (ftr && fsp) { conv = true; break; }  // states now identical
        }
        res = conv ? res_ws[row * SEGS + s] : res_tr;
    }
}

extern "C" void kernel_launch(void* const* d_in, const int* in_sizes, int n_in,
                              void* d_out, int out_size, void* d_ws, size_t ws_size,
                              hipStream_t stream)
{
    const float* x    = (const float*)d_in[0];
    const float* thrp = (const float*)d_in[1];
    float*       out  = (float*)d_out;
    float*       ws   = (float*)d_ws;    // 65536*8 floats = 2 MB

    const int rows  = in_sizes[0] / T_LEN;          // 65536
    const int grid1 = rows * SEGS / BLOCK1;         // 2048
    const int grid2 = rows / BLOCK2;                // 256

    delta_seg_kernel<<<grid1, BLOCK1, 0, stream>>>(x, thrp, out, ws);
    delta_fix_kernel<<<grid2, BLOCK2, 0, stream>>>(x, thrp, out, ws);
}